// Round 12
// baseline (634.895 us; speedup 1.0000x reference)
//
#include <hip/hip_runtime.h>
#include <hip/hip_cooperative_groups.h>
#include <hip/hip_bf16.h>

namespace cg = cooperative_groups;

// B=2, C=256, N=4096, heads=4, D=64, 3D=192, M_embed=768
#define NH   4
#define D_   64
#define N_   4096
#define C_   256
#define ME   768
#define QSCALE 0.18033688f   // 0.125 * log2(e): softmax done in exp2 domain

typedef float    f32x4  __attribute__((ext_vector_type(4)));
typedef float    f32x16 __attribute__((ext_vector_type(16)));
typedef _Float16 f16x8  __attribute__((ext_vector_type(8)));
typedef _Float16 f16x4  __attribute__((ext_vector_type(4)));

// ===========================================================================
// MEGA-KERNEL (cooperative): all 5 phases in ONE launch, grid.sync between.
// Grid 1024 x 256. Resources: LDS 19456 B (8 blk/CU), VGPR<=128 (4 blk/CU)
// -> 1024 blocks co-resident (4/CU), the cooperative-launch requirement.
// ===========================================================================
__global__ __launch_bounds__(256, 4) void mega_kernel(
    const float* __restrict__ x, const float* __restrict__ w_embed,
    const float* __restrict__ b_embed, const float* __restrict__ w_out,
    const float* __restrict__ b_out,
    _Float16* __restrict__ xT, _Float16* __restrict__ wh,
    _Float16* __restrict__ w_outT, _Float16* __restrict__ qT,
    _Float16* __restrict__ kT, _Float16* __restrict__ vB,
    _Float16* __restrict__ opart, float* __restrict__ mpart,
    float* __restrict__ lpart, _Float16* __restrict__ yT,
    float* __restrict__ out) {

    __shared__ __align__(16) union SM {
        float T[64][68];                               // prep        17408 B
        struct { _Float16 A[64][40], X[64][40]; } g;   // gemm stage  10240 B
        float Os[64][68];                              // gemm epi    17408 B
        struct { _Float16 K[64][76], V[64][76]; } a;   // attn        19456 B
        _Float16 AOs[128][76];                         // attn epi    19456 B
    } sm;

    cg::grid_group grid = cg::this_grid();
    const int t = threadIdx.x;
    const int bx = blockIdx.x;
    const int lane = t & 63, w = t >> 6;

    // ---------------- Phase A: prep (x->xT f16 [n][c]; w->wh; w_out->w_outT)
    {
        if (bx < 512) {
            const int n0 = (bx & 63) * 64, c0 = ((bx >> 6) & 3) * 64, b = bx >> 8;
            const float* xp = x + ((size_t)b * C_ + c0) * N_ + n0;
            #pragma unroll
            for (int r = 0; r < 4; ++r) {
                int idx = r * 256 + t;
                int c = idx >> 4, ng = (idx & 15) * 4;
                *(f32x4*)&sm.T[c][ng] = *(const f32x4*)(xp + (size_t)c * N_ + ng);
            }
            __syncthreads();
            _Float16* dp = xT + ((size_t)b * N_ + n0) * C_ + c0;
            #pragma unroll
            for (int r = 0; r < 2; ++r) {
                int idx = r * 256 + t;
                int n = idx >> 3, cg2 = (idx & 7) * 8;
                f16x8 v;
                #pragma unroll
                for (int j = 0; j < 8; ++j) v[j] = (_Float16)sm.T[cg2 + j][n];
                *(f16x8*)(dp + (size_t)n * C_ + cg2) = v;
            }
        } else if (bx < 608) {
            int gid = (bx - 512) * 256 + t;
            const float* s = w_embed + (size_t)gid * 8;
            f32x4 a = *(const f32x4*)s, b2 = *(const f32x4*)(s + 4);
            f16x8 v = { (_Float16)a[0], (_Float16)a[1], (_Float16)a[2], (_Float16)a[3],
                        (_Float16)b2[0], (_Float16)b2[1], (_Float16)b2[2], (_Float16)b2[3] };
            *(f16x8*)(wh + (size_t)gid * 8) = v;
        } else if (bx < 624) {
            int tile = bx - 608;
            int tc = tile & 3, tk = tile >> 2;
            #pragma unroll
            for (int r = 0; r < 4; ++r) {
                int idx = r * 256 + t;
                int kl = idx >> 4, cl = (idx & 15) * 4;
                *(f32x4*)&sm.T[kl][cl] = *(const f32x4*)(w_out + (size_t)(tk * 64 + kl) * C_ + tc * 64 + cl);
            }
            __syncthreads();
            #pragma unroll
            for (int r = 0; r < 2; ++r) {
                int idx = r * 256 + t;
                int cl = idx >> 3, kg = (idx & 7) * 8;
                f16x8 v;
                #pragma unroll
                for (int j = 0; j < 8; ++j) v[j] = (_Float16)sm.T[kg + j][cl];
                *(f16x8*)(w_outT + (size_t)(tc * 64 + cl) * C_ + tk * 64 + kg) = v;
            }
        }
    }
    grid.sync();

    // ---------------- Phase B: QKV GEMM (1536 virtual blocks, v-loop)
    {
        const int quad = lane >> 4, l16 = lane & 15;
        const int srow = t >> 2, skoff = (t & 3) * 8;
        for (int v = bx; v < 1536; v += 1024) {
            const int n0 = (v & 63) * 64;
            const int mtb = v >> 6;
            const int mt = mtb % 12, b = mtb / 12;
            const int m0 = mt * 64;
            const int h = mt / 3, r3 = mt - h * 3;
            const float oscale = (r3 == 0) ? QSCALE : 1.0f;
            const _Float16* ap = wh + (size_t)(m0 + srow) * C_ + skoff;
            const _Float16* xp = xT + ((size_t)b * N_ + n0 + srow) * C_ + skoff;
            f16x8 apre = *(const f16x8*)(ap);
            f16x8 xpre = *(const f16x8*)(xp);
            f32x4 acc[4] = {};
            for (int k0 = 0; k0 < C_; k0 += 32) {
                __syncthreads();
                *(f16x8*)&sm.g.A[srow][skoff] = apre;
                *(f16x8*)&sm.g.X[srow][skoff] = xpre;
                __syncthreads();
                if (k0 + 32 < C_) {
                    apre = *(const f16x8*)(ap + k0 + 32);
                    xpre = *(const f16x8*)(xp + k0 + 32);
                }
                f16x8 af = *(const f16x8*)&sm.g.A[w * 16 + l16][quad * 8];
                #pragma unroll
                for (int nb = 0; nb < 4; ++nb) {
                    f16x8 bf = *(const f16x8*)&sm.g.X[nb * 16 + l16][quad * 8];
                    acc[nb] = __builtin_amdgcn_mfma_f32_16x16x32_f16(af, bf, acc[nb], 0, 0, 0);
                }
            }
            float bias[4];
            #pragma unroll
            for (int rg = 0; rg < 4; ++rg) bias[rg] = b_embed[m0 + w * 16 + quad * 4 + rg];
            __syncthreads();
            #pragma unroll
            for (int nb = 0; nb < 4; ++nb)
                #pragma unroll
                for (int rg = 0; rg < 4; ++rg)
                    sm.Os[w * 16 + quad * 4 + rg][nb * 16 + l16] = (acc[nb][rg] + bias[rg]) * oscale;
            __syncthreads();
            const int bh = b * NH + h;
            if (r3 < 2) {
                _Float16* dst = (r3 ? kT : qT) + ((size_t)bh * N_ + n0) * D_;
                #pragma unroll
                for (int r = 0; r < 2; ++r) {
                    int idx = r * 256 + t;
                    int n = idx >> 3, mg = (idx & 7) * 8;
                    f16x8 vv;
                    #pragma unroll
                    for (int j = 0; j < 8; ++j) vv[j] = (_Float16)sm.Os[mg + j][n];
                    *(f16x8*)(dst + (size_t)n * D_ + mg) = vv;
                }
            } else {
                _Float16* dst = vB + (size_t)bh * D_ * N_ + n0;
                #pragma unroll
                for (int r = 0; r < 2; ++r) {
                    int idx = r * 256 + t;
                    int d = idx >> 3, ng = (idx & 7) * 8;
                    f32x4 a = *(const f32x4*)&sm.Os[d][ng];
                    f32x4 b2 = *(const f32x4*)&sm.Os[d][ng + 4];
                    f16x8 vv = { (_Float16)a[0], (_Float16)a[1], (_Float16)a[2], (_Float16)a[3],
                                 (_Float16)b2[0], (_Float16)b2[1], (_Float16)b2[2], (_Float16)b2[3] };
                    *(f16x8*)(dst + (size_t)d * N_ + ng) = vv;
                }
            }
            __syncthreads();   // Os reads done before next v overwrites sm.g
        }
    }
    grid.sync();

    // ---------------- Phase C: flash attention (r11 verified body, nsp=4)
    {
        const int qt = bx & 31, h = (bx >> 5) & 3, z = bx >> 7;
        const int b = z >> 2, s = z & 3;
        const int bh = b * NH + h, sbh = s * 8 + bh;
        const _Float16* kp = kT + (size_t)bh * N_ * D_;
        const _Float16* vp = vB + (size_t)bh * D_ * N_;
        const int l32 = lane & 31, hl = lane >> 5;
        const int srow = t >> 3, scol = (t & 7) * 8;

        const _Float16* qp = qT + ((size_t)bh * N_ + qt * 128 + w * 32 + l32) * D_;
        f16x8 qf[4];
        #pragma unroll
        for (int kc = 0; kc < 4; ++kc) qf[kc] = *(const f16x8*)(qp + kc * 16 + hl * 8);

        f32x16 oacc0 = {}, oacc1 = {};
        float m_run = 0.f, l_run = 0.f;

        const int jt_lo = s * 16, jt_hi = jt_lo + 16;
        f16x8 kpre[2], vpre[2];
        #pragma unroll
        for (int r = 0; r < 2; ++r) {
            int row = srow + r * 32;
            kpre[r] = *(const f16x8*)(kp + (size_t)(jt_lo * 64 + row) * D_ + scol);
            vpre[r] = *(const f16x8*)(vp + (size_t)row * N_ + jt_lo * 64 + scol);
        }

        for (int jt = jt_lo; jt < jt_hi; ++jt) {
            __syncthreads();
            #pragma unroll
            for (int r = 0; r < 2; ++r) {
                int row = srow + r * 32;
                *(f16x8*)&sm.a.K[row][scol] = kpre[r];
                *(f16x8*)&sm.a.V[row][scol] = vpre[r];
            }
            __syncthreads();
            if (jt + 1 < jt_hi) {
                #pragma unroll
                for (int r = 0; r < 2; ++r) {
                    int row = srow + r * 32;
                    kpre[r] = *(const f16x8*)(kp + (size_t)((jt + 1) * 64 + row) * D_ + scol);
                    vpre[r] = *(const f16x8*)(vp + (size_t)row * N_ + (jt + 1) * 64 + scol);
                }
            }

            f32x16 sa0 = {}, sa1 = {};
            #pragma unroll
            for (int kc = 0; kc < 4; ++kc) {
                f16x8 kf0 = *(const f16x8*)&sm.a.K[l32][kc * 16 + hl * 8];
                sa0 = __builtin_amdgcn_mfma_f32_32x32x16_f16(kf0, qf[kc], sa0, 0, 0, 0);
                f16x8 kf1 = *(const f16x8*)&sm.a.K[32 + l32][kc * 16 + hl * 8];
                sa1 = __builtin_amdgcn_mfma_f32_32x32x16_f16(kf1, qf[kc], sa1, 0, 0, 0);
            }

            if (jt == jt_lo) {
                f32x16 mm;
                #pragma unroll
                for (int r = 0; r < 16; ++r) mm[r] = fmaxf(sa0[r], sa1[r]);
                f32x4 m4;
                #pragma unroll
                for (int r = 0; r < 4; ++r)
                    m4[r] = fmaxf(fmaxf(mm[r], mm[r + 4]), fmaxf(mm[r + 8], mm[r + 12]));
                float mx = fmaxf(fmaxf(m4[0], m4[1]), fmaxf(m4[2], m4[3]));
                mx = fmaxf(mx, __shfl_xor(mx, 32));
                m_run = mx + 8.0f;
            }

            #pragma unroll
            for (int r = 0; r < 16; ++r) sa0[r] = __builtin_amdgcn_exp2f(sa0[r] - m_run);
            #pragma unroll
            for (int r = 0; r < 16; ++r) sa1[r] = __builtin_amdgcn_exp2f(sa1[r] - m_run);
            f32x16 sv = sa0 + sa1;
            f32x4 s4;
            #pragma unroll
            for (int r = 0; r < 4; ++r) s4[r] = (sv[r] + sv[r + 4]) + (sv[r + 8] + sv[r + 12]);
            float rs = (s4[0] + s4[1]) + (s4[2] + s4[3]);
            rs += __shfl_xor(rs, 32);
            l_run += rs;

            #pragma unroll
            for (int jb = 0; jb < 2; ++jb) {
                const f32x16& sa = jb ? sa1 : sa0;
                union BU { f16x4 v; int d[2]; } bf[4];
                #pragma unroll
                for (int q = 0; q < 8; ++q)
                    bf[q >> 1].d[q & 1] =
                        __builtin_bit_cast(int, __builtin_amdgcn_cvt_pkrtz(sa[2 * q], sa[2 * q + 1]));
                #pragma unroll
                for (int c = 0; c < 4; ++c) {
                    const int vcol = jb * 32 + c * 8 + hl * 4;
                    f16x4 va = *(const f16x4*)&sm.a.V[l32][vcol];
                    oacc0 = __builtin_amdgcn_mfma_f32_32x32x8f16(va, bf[c].v, oacc0, 0, 0, 0);
                    f16x4 vb = *(const f16x4*)&sm.a.V[32 + l32][vcol];
                    oacc1 = __builtin_amdgcn_mfma_f32_32x32x8f16(vb, bf[c].v, oacc1, 0, 0, 0);
                }
            }
        }

        float linv = 1.f / l_run;
        if (hl == 0) {
            mpart[(size_t)sbh * N_ + qt * 128 + w * 32 + l32] = m_run;
            lpart[(size_t)sbh * N_ + qt * 128 + w * 32 + l32] = l_run;
        }
        __syncthreads();
        #pragma unroll
        for (int db = 0; db < 2; ++db) {
            const f32x16& oc = db ? oacc1 : oacc0;
            #pragma unroll
            for (int rq = 0; rq < 4; ++rq) {
                f16x4 pv = { (_Float16)(oc[rq * 4 + 0] * linv), (_Float16)(oc[rq * 4 + 1] * linv),
                             (_Float16)(oc[rq * 4 + 2] * linv), (_Float16)(oc[rq * 4 + 3] * linv) };
                *(f16x4*)&sm.AOs[w * 32 + l32][db * 32 + rq * 8 + hl * 4] = pv;
            }
        }
        __syncthreads();
        _Float16* op = opart + ((size_t)sbh * N_ + qt * 128) * D_;
        #pragma unroll
        for (int r = 0; r < 4; ++r) {
            int idx = r * 256 + t;
            int i = idx >> 3, ch = (idx & 7) * 8;
            *(f16x8*)(op + (size_t)i * D_ + ch) = *(const f16x8*)&sm.AOs[i][ch];
        }
    }
    grid.sync();

    // ---------------- Phase D: combine 4 splits -> yT f16 [b][n][256]
    {
        const int cx = bx & 127, bhi = bx >> 7;
        const int idx = cx * 256 + t;
        const int n = idx >> 3, dg = (idx & 7) * 8;
        const int b = bhi >> 2, h = bhi & 3;
        float mv[4], lv[4];
        float M = -3.0e38f;
        #pragma unroll
        for (int sI = 0; sI < 4; ++sI) {
            mv[sI] = mpart[(size_t)(sI * 8 + bhi) * N_ + n];
            lv[sI] = lpart[(size_t)(sI * 8 + bhi) * N_ + n];
            M = fmaxf(M, mv[sI]);
        }
        float ws[4], sum = 0.f;
        #pragma unroll
        for (int sI = 0; sI < 4; ++sI) {
            ws[sI] = __builtin_amdgcn_exp2f(mv[sI] - M) * lv[sI];
            sum += ws[sI];
        }
        float inv = 1.f / sum;
        float accf[8] = {};
        #pragma unroll
        for (int sI = 0; sI < 4; ++sI) {
            f16x8 ov = *(const f16x8*)(opart + ((size_t)(sI * 8 + bhi) * N_ + n) * D_ + dg);
            float wsv = ws[sI] * inv;
            #pragma unroll
            for (int j = 0; j < 8; ++j) accf[j] += wsv * (float)ov[j];
        }
        f16x8 v;
        #pragma unroll
        for (int j = 0; j < 8; ++j) v[j] = (_Float16)accf[j];
        *(f16x8*)(yT + ((size_t)b * N_ + n) * C_ + h * 64 + dg) = v;
    }
    grid.sync();

    // ---------------- Phase E: projection + bias + residual (512 virtual)
    if (bx < 512) {
        const int n0 = (bx & 63) * 64, c0 = ((bx >> 6) & 3) * 64, b = bx >> 8;
        const int quad = lane >> 4, l16 = lane & 15;
        const int srow = t >> 2, skoff = (t & 3) * 8;
        const _Float16* ap = w_outT + (size_t)(c0 + srow) * C_ + skoff;
        const _Float16* yp = yT + ((size_t)b * N_ + n0 + srow) * C_ + skoff;
        f16x8 apre = *(const f16x8*)(ap);
        f16x8 ypre = *(const f16x8*)(yp);
        f32x4 acc[4] = {};
        for (int k0 = 0; k0 < C_; k0 += 32) {
            __syncthreads();
            *(f16x8*)&sm.g.A[srow][skoff] = apre;
            *(f16x8*)&sm.g.X[srow][skoff] = ypre;
            __syncthreads();
            if (k0 + 32 < C_) {
                apre = *(const f16x8*)(ap + k0 + 32);
                ypre = *(const f16x8*)(yp + k0 + 32);
            }
            f16x8 af = *(const f16x8*)&sm.g.A[w * 16 + l16][quad * 8];
            #pragma unroll
            for (int nb = 0; nb < 4; ++nb) {
                f16x8 bf = *(const f16x8*)&sm.g.X[nb * 16 + l16][quad * 8];
                acc[nb] = __builtin_amdgcn_mfma_f32_16x16x32_f16(af, bf, acc[nb], 0, 0, 0);
            }
        }
        float bias[4];
        #pragma unroll
        for (int rg = 0; rg < 4; ++rg) bias[rg] = b_out[c0 + w * 16 + quad * 4 + rg];
        __syncthreads();
        #pragma unroll
        for (int nb = 0; nb < 4; ++nb)
            #pragma unroll
            for (int rg = 0; rg < 4; ++rg)
                sm.Os[w * 16 + quad * 4 + rg][nb * 16 + l16] = acc[nb][rg] + bias[rg];
        __syncthreads();
        const float* xp = x + ((size_t)b * C_ + c0) * N_ + n0;
        float* op = out + ((size_t)b * C_ + c0) * N_ + n0;
        #pragma unroll
        for (int r = 0; r < 4; ++r) {
            int idx = r * 256 + t;
            int c = idx >> 4, ng = (idx & 15) * 4;
            f32x4 v  = *(const f32x4*)&sm.Os[c][ng];
            f32x4 xv = *(const f32x4*)(xp + (size_t)c * N_ + ng);
            f32x4 o  = { v[0] + xv[0], v[1] + xv[1], v[2] + xv[2], v[3] + xv[3] };
            *(f32x4*)(op + (size_t)c * N_ + ng) = o;
        }
    }
}

// ===========================================================================
// FALLBACK PATH: r11's 5 separate kernels (used if cooperative launch is
// unavailable). Verbatim from round 11 (143.5 us verified).
// ===========================================================================
__global__ __launch_bounds__(256) void prep_kernel(const float* __restrict__ x,
                                                   const float* __restrict__ w_embed,
                                                   const float* __restrict__ w_out,
                                                   _Float16* __restrict__ xT,
                                                   _Float16* __restrict__ wh,
                                                   _Float16* __restrict__ w_outT) {
    __shared__ float T[64][68];
    const int t = threadIdx.x, bx = blockIdx.x;
    if (bx < 512) {
        const int n0 = (bx & 63) * 64, c0 = ((bx >> 6) & 3) * 64, b = bx >> 8;
        const float* xp = x + ((size_t)b * C_ + c0) * N_ + n0;
        #pragma unroll
        for (int r = 0; r < 4; ++r) {
            int idx = r * 256 + t;
            int c = idx >> 4, ng = (idx & 15) * 4;
            *(f32x4*)&T[c][ng] = *(const f32x4*)(xp + (size_t)c * N_ + ng);
        }
        __syncthreads();
        _Float16* dp = xT + ((size_t)b * N_ + n0) * C_ + c0;
        #pragma unroll
        for (int r = 0; r < 2; ++r) {
            int idx = r * 256 + t;
            int n = idx >> 3, cg = (idx & 7) * 8;
            f16x8 v;
            #pragma unroll
            for (int j = 0; j < 8; ++j) v[j] = (_Float16)T[cg + j][n];
            *(f16x8*)(dp + (size_t)n * C_ + cg) = v;
        }
    } else if (bx < 608) {
        int gid = (bx - 512) * 256 + t;
        const float* s = w_embed + (size_t)gid * 8;
        f32x4 a = *(const f32x4*)s, b2 = *(const f32x4*)(s + 4);
        f16x8 v = { (_Float16)a[0], (_Float16)a[1], (_Float16)a[2], (_Float16)a[3],
                    (_Float16)b2[0], (_Float16)b2[1], (_Float16)b2[2], (_Float16)b2[3] };
        *(f16x8*)(wh + (size_t)gid * 8) = v;
    } else {
        int tile = bx - 608;
        int tc = tile & 3, tk = tile >> 2;
        #pragma unroll
        for (int r = 0; r < 4; ++r) {
            int idx = r * 256 + t;
            int kl = idx >> 4, cl = (idx & 15) * 4;
            *(f32x4*)&T[kl][cl] = *(const f32x4*)(w_out + (size_t)(tk * 64 + kl) * C_ + tc * 64 + cl);
        }
        __syncthreads();
        #pragma unroll
        for (int r = 0; r < 2; ++r) {
            int idx = r * 256 + t;
            int cl = idx >> 3, kg = (idx & 7) * 8;
            f16x8 v;
            #pragma unroll
            for (int j = 0; j < 8; ++j) v[j] = (_Float16)T[kg + j][cl];
            *(f16x8*)(w_outT + (size_t)(tc * 64 + cl) * C_ + tk * 64 + kg) = v;
        }
    }
}

__global__ __launch_bounds__(256) void qkv_gemm(const _Float16* __restrict__ xT,
                                                const _Float16* __restrict__ wh,
                                                const float* __restrict__ b_embed,
                                                _Float16* __restrict__ qT,
                                                _Float16* __restrict__ kT,
                                                _Float16* __restrict__ vB) {
    __shared__ __align__(16) union SM {
        struct { _Float16 A[64][40], X[64][40]; } s;
        float Os[64][68];
    } sm;
    const int n0 = blockIdx.x * 64, mt = blockIdx.y, b = blockIdx.z;
    const int m0 = mt * 64;
    const int t = threadIdx.x;
    const int lane = t & 63, w = t >> 6, quad = lane >> 4, l16 = lane & 15;
    const int srow = t >> 2, skoff = (t & 3) * 8;
    const int h = mt / 3, r3 = mt - h * 3;
    const float oscale = (r3 == 0) ? QSCALE : 1.0f;
    const _Float16* ap = wh + (size_t)(m0 + srow) * C_ + skoff;
    const _Float16* xp = xT + ((size_t)b * N_ + n0 + srow) * C_ + skoff;
    f16x8 apre = *(const f16x8*)(ap);
    f16x8 xpre = *(const f16x8*)(xp);
    f32x4 acc[4] = {};
    for (int k0 = 0; k0 < C_; k0 += 32) {
        __syncthreads();
        *(f16x8*)&sm.s.A[srow][skoff] = apre;
        *(f16x8*)&sm.s.X[srow][skoff] = xpre;
        __syncthreads();
        if (k0 + 32 < C_) {
            apre = *(const f16x8*)(ap + k0 + 32);
            xpre = *(const f16x8*)(xp + k0 + 32);
        }
        f16x8 af = *(const f16x8*)&sm.s.A[w * 16 + l16][quad * 8];
        #pragma unroll
        for (int nb = 0; nb < 4; ++nb) {
            f16x8 bf = *(const f16x8*)&sm.s.X[nb * 16 + l16][quad * 8];
            acc[nb] = __builtin_amdgcn_mfma_f32_16x16x32_f16(af, bf, acc[nb], 0, 0, 0);
        }
    }
    float bias[4];
    #pragma unroll
    for (int rg = 0; rg < 4; ++rg) bias[rg] = b_embed[m0 + w * 16 + quad * 4 + rg];
    __syncthreads();
    #pragma unroll
    for (int nb = 0; nb < 4; ++nb)
        #pragma unroll
        for (int rg = 0; rg < 4; ++rg)
            sm.Os[w * 16 + quad * 4 + rg][nb * 16 + l16] = (acc[nb][rg] + bias[rg]) * oscale;
    __syncthreads();
    const int bh = b * NH + h;
    if (r3 < 2) {
        _Float16* dst = (r3 ? kT : qT) + ((size_t)bh * N_ + n0) * D_;
        #pragma unroll
        for (int r = 0; r < 2; ++r) {
            int idx = r * 256 + t;
            int n = idx >> 3, mg = (idx & 7) * 8;
            f16x8 v;
            #pragma unroll
            for (int j = 0; j < 8; ++j) v[j] = (_Float16)sm.Os[mg + j][n];
            *(f16x8*)(dst + (size_t)n * D_ + mg) = v;
        }
    } else {
        _Float16* dst = vB + (size_t)bh * D_ * N_ + n0;
        #pragma unroll
        for (int r = 0; r < 2; ++r) {
            int idx = r * 256 + t;
            int d = idx >> 3, ng = (idx & 7) * 8;
            f32x4 a = *(const f32x4*)&sm.Os[d][ng];
            f32x4 b2 = *(const f32x4*)&sm.Os[d][ng + 4];
            f16x8 v = { (_Float16)a[0], (_Float16)a[1], (_Float16)a[2], (_Float16)a[3],
                        (_Float16)b2[0], (_Float16)b2[1], (_Float16)b2[2], (_Float16)b2[3] };
            *(f16x8*)(dst + (size_t)d * N_ + ng) = v;
        }
    }
}

__global__ __launch_bounds__(256, 4) void attn_kernel(const _Float16* __restrict__ qT,
                                                      const _Float16* __restrict__ kT,
                                                      const _Float16* __restrict__ vB,
                                                      _Float16* __restrict__ opart,
                                                      float* __restrict__ mpart,
                                                      float* __restrict__ lpart,
                                                      int splog) {
    __shared__ __align__(16) union SM {
        struct { _Float16 K[64][76], V[64][76]; } s;
        _Float16 Os[128][76];
    } sm;
    const int t = threadIdx.x;
    const int nsp = 1 << splog;
    const int qt = blockIdx.x, h = blockIdx.y;
    const int b = blockIdx.z >> splog, s = blockIdx.z & (nsp - 1);
    const int bh = b * NH + h, sbh = s * 8 + bh;
    const _Float16* kp = kT + (size_t)bh * N_ * D_;
    const _Float16* vp = vB + (size_t)bh * D_ * N_;
    const int lane = t & 63, w = t >> 6, l32 = lane & 31, hl = lane >> 5;
    const int srow = t >> 3, scol = (t & 7) * 8;

    const _Float16* qp = qT + ((size_t)bh * N_ + qt * 128 + w * 32 + l32) * D_;
    f16x8 qf[4];
    #pragma unroll
    for (int kc = 0; kc < 4; ++kc) qf[kc] = *(const f16x8*)(qp + kc * 16 + hl * 8);

    f32x16 oacc0 = {}, oacc1 = {};
    float m_run = 0.f, l_run = 0.f;

    const int niter = 64 >> splog;
    const int jt_lo = s * niter, jt_hi = jt_lo + niter;
    f16x8 kpre[2], vpre[2];
    #pragma unroll
    for (int r = 0; r < 2; ++r) {
        int row = srow + r * 32;
        kpre[r] = *(const f16x8*)(kp + (size_t)(jt_lo * 64 + row) * D_ + scol);
        vpre[r] = *(const f16x8*)(vp + (size_t)row * N_ + jt_lo * 64 + scol);
    }

    for (int jt = jt_lo; jt < jt_hi; ++jt) {
        __syncthreads();
        #pragma unroll
        for (int r = 0; r < 2; ++r) {
            int row = srow + r * 32;
            *(f16x8*)&sm.s.K[row][scol] = kpre[r];
            *(f16x8*)&sm.s.V[row][scol] = vpre[r];
        }
        __syncthreads();
        if (jt + 1 < jt_hi) {
            #pragma unroll
            for (int r = 0; r < 2; ++r) {
                int row = srow + r * 32;
                kpre[r] = *(const f16x8*)(kp + (size_t)((jt + 1) * 64 + row) * D_ + scol);
                vpre[r] = *(const f16x8*)(vp + (size_t)row * N_ + (jt + 1) * 64 + scol);
            }
        }
        f32x16 sa0 = {}, sa1 = {};
        #pragma unroll
        for (int kc = 0; kc < 4; ++kc) {
            f16x8 kf0 = *(const f16x8*)&sm.s.K[l32][kc * 16 + hl * 8];
            sa0 = __builtin_amdgcn_mfma_f32_32x32x16_f16(kf0, qf[kc], sa0, 0, 0, 0);
            f16x8 kf1 = *(const f16x8*)&sm.s.K[32 + l32][kc * 16 + hl * 8];
            sa1 = __builtin_amdgcn_mfma_f32_32x32x16_f16(kf1, qf[kc], sa1, 0, 0, 0);
        }
        if (jt == jt_lo) {
            f32x16 mm;
            #pragma unroll
            for (int r = 0; r < 16; ++r) mm[r] = fmaxf(sa0[r], sa1[r]);
            f32x4 m4;
            #pragma unroll
            for (int r = 0; r < 4; ++r)
                m4[r] = fmaxf(fmaxf(mm[r], mm[r + 4]), fmaxf(mm[r + 8], mm[r + 12]));
            float mx = fmaxf(fmaxf(m4[0], m4[1]), fmaxf(m4[2], m4[3]));
            mx = fmaxf(mx, __shfl_xor(mx, 32));
            m_run = mx + 8.0f;
        }
        #pragma unroll
        for (int r = 0; r < 16; ++r) sa0[r] = __builtin_amdgcn_exp2f(sa0[r] - m_run);
        #pragma unroll
        for (int r = 0; r < 16; ++r) sa1[r] = __builtin_amdgcn_exp2f(sa1[r] - m_run);
        f32x16 sv = sa0 + sa1;
        f32x4 s4;
        #pragma unroll
        for (int r = 0; r < 4; ++r) s4[r] = (sv[r] + sv[r + 4]) + (sv[r + 8] + sv[r + 12]);
        float rs = (s4[0] + s4[1]) + (s4[2] + s4[3]);
        rs += __shfl_xor(rs, 32);
        l_run += rs;
        #pragma unroll
        for (int jb = 0; jb < 2; ++jb) {
            const f32x16& sa = jb ? sa1 : sa0;
            union BU { f16x4 v; int d[2]; } bf[4];
            #pragma unroll
            for (int q = 0; q < 8; ++q)
                bf[q >> 1].d[q & 1] =
                    __builtin_bit_cast(int, __builtin_amdgcn_cvt_pkrtz(sa[2 * q], sa[2 * q + 1]));
            #pragma unroll
            for (int c = 0; c < 4; ++c) {
                const int vcol = jb * 32 + c * 8 + hl * 4;
                f16x4 va = *(const f16x4*)&sm.s.V[l32][vcol];
                oacc0 = __builtin_amdgcn_mfma_f32_32x32x8f16(va, bf[c].v, oacc0, 0, 0, 0);
                f16x4 vb = *(const f16x4*)&sm.s.V[32 + l32][vcol];
                oacc1 = __builtin_amdgcn_mfma_f32_32x32x8f16(vb, bf[c].v, oacc1, 0, 0, 0);
            }
        }
    }
    float linv = 1.f / l_run;
    if (hl == 0) {
        mpart[(size_t)sbh * N_ + qt * 128 + w * 32 + l32] = m_run;
        lpart[(size_t)sbh * N_ + qt * 128 + w * 32 + l32] = l_run;
    }
    __syncthreads();
    #pragma unroll
    for (int db = 0; db < 2; ++db) {
        const f32x16& oc = db ? oacc1 : oacc0;
        #pragma unroll
        for (int rq = 0; rq < 4; ++rq) {
            f16x4 pv = { (_Float16)(oc[rq * 4 + 0] * linv), (_Float16)(oc[rq * 4 + 1] * linv),
                         (_Float16)(oc[rq * 4 + 2] * linv), (_Float16)(oc[rq * 4 + 3] * linv) };
            *(f16x4*)&sm.Os[w * 32 + l32][db * 32 + rq * 8 + hl * 4] = pv;
        }
    }
    __syncthreads();
    _Float16* op = opart + ((size_t)sbh * N_ + qt * 128) * D_;
    #pragma unroll
    for (int r = 0; r < 4; ++r) {
        int idx = r * 256 + t;
        int i = idx >> 3, ch = (idx & 7) * 8;
        *(f16x8*)(op + (size_t)i * D_ + ch) = *(const f16x8*)&sm.Os[i][ch];
    }
}

__global__ __launch_bounds__(256) void combine_kernel(const _Float16* __restrict__ opart,
                                                      const float* __restrict__ mpart,
                                                      const float* __restrict__ lpart,
                                                      _Float16* __restrict__ yT,
                                                      int nsp) {
    const int bhi = blockIdx.y;
    const int idx = blockIdx.x * 256 + threadIdx.x;
    const int n = idx >> 3, dg = (idx & 7) * 8;
    const int b = bhi >> 2, h = bhi & 3;
    float mv[8], lv[8];
    float M = -3.0e38f;
    for (int sI = 0; sI < nsp; ++sI) {
        mv[sI] = mpart[(size_t)(sI * 8 + bhi) * N_ + n];
        lv[sI] = lpart[(size_t)(sI * 8 + bhi) * N_ + n];
        M = fmaxf(M, mv[sI]);
    }
    float ws[8], sum = 0.f;
    for (int sI = 0; sI < nsp; ++sI) {
        ws[sI] = __builtin_amdgcn_exp2f(mv[sI] - M) * lv[sI];
        sum += ws[sI];
    }
    float inv = 1.f / sum;
    float accf[8] = {};
    for (int sI = 0; sI < nsp; ++sI) {
        f16x8 ov = *(const f16x8*)(opart + ((size_t)(sI * 8 + bhi) * N_ + n) * D_ + dg);
        float wsv = ws[sI] * inv;
        #pragma unroll
        for (int j = 0; j < 8; ++j) accf[j] += wsv * (float)ov[j];
    }
    f16x8 v;
    #pragma unroll
    for (int j = 0; j < 8; ++j) v[j] = (_Float16)accf[j];
    *(f16x8*)(yT + ((size_t)b * N_ + n) * C_ + h * 64 + dg) = v;
}

__global__ __launch_bounds__(256) void proj_gemm(const _Float16* __restrict__ yT,
                                                 const _Float16* __restrict__ w_outT,
                                                 const float* __restrict__ b_out,
                                                 const float* __restrict__ x,
                                                 float* __restrict__ out) {
    __shared__ __align__(16) union SM {
        struct { _Float16 A[64][40], Y[64][40]; } s;
        float Os[64][68];
    } sm;
    const int n0 = blockIdx.x * 64, c0 = blockIdx.y * 64, b = blockIdx.z;
    const int t = threadIdx.x;
    const int lane = t & 63, w = t >> 6, quad = lane >> 4, l16 = lane & 15;
    const int srow = t >> 2, skoff = (t & 3) * 8;
    const _Float16* ap = w_outT + (size_t)(c0 + srow) * C_ + skoff;
    const _Float16* yp = yT + ((size_t)b * N_ + n0 + srow) * C_ + skoff;
    f16x8 apre = *(const f16x8*)(ap);
    f16x8 ypre = *(const f16x8*)(yp);
    f32x4 acc[4] = {};
    for (int k0 = 0; k0 < C_; k0 += 32) {
        __syncthreads();
        *(f16x8*)&sm.s.A[srow][skoff] = apre;
        *(f16x8*)&sm.s.Y[srow][skoff] = ypre;
        __syncthreads();
        if (k0 + 32 < C_) {
            apre = *(const f16x8*)(ap + k0 + 32);
            ypre = *(const f16x8*)(yp + k0 + 32);
        }
        f16x8 af = *(const f16x8*)&sm.s.A[w * 16 + l16][quad * 8];
        #pragma unroll
        for (int nb = 0; nb < 4; ++nb) {
            f16x8 bf = *(const f16x8*)&sm.s.Y[nb * 16 + l16][quad * 8];
            acc[nb] = __builtin_amdgcn_mfma_f32_16x16x32_f16(af, bf, acc[nb], 0, 0, 0);
        }
    }
    float bias[4];
    #pragma unroll
    for (int rg = 0; rg < 4; ++rg) bias[rg] = b_out[c0 + w * 16 + quad * 4 + rg];
    __syncthreads();
    #pragma unroll
    for (int nb = 0; nb < 4; ++nb)
        #pragma unroll
        for (int rg = 0; rg < 4; ++rg)
            sm.Os[w * 16 + quad * 4 + rg][nb * 16 + l16] = acc[nb][rg] + bias[rg];
    __syncthreads();
    const float* xp = x + ((size_t)b * C_ + c0) * N_ + n0;
    float* op = out + ((size_t)b * C_ + c0) * N_ + n0;
    #pragma unroll
    for (int r = 0; r < 4; ++r) {
        int idx = r * 256 + t;
        int c = idx >> 4, ng = (idx & 15) * 4;
        f32x4 v  = *(const f32x4*)&sm.Os[c][ng];
        f32x4 xv = *(const f32x4*)(xp + (size_t)c * N_ + ng);
        f32x4 o  = { v[0] + xv[0], v[1] + xv[1], v[2] + xv[2], v[3] + xv[3] };
        *(f32x4*)(op + (size_t)c * N_ + ng) = o;
    }
}

// ---------------------------------------------------------------------------
// Workspace (f16 element offsets), nsp=4 (~35 MB):
//   xT 0 (2,097,152)  <- yT ALIASES this region (xT dead after qkv phase)
//   wh 2,097,152 | w_outT 2,293,760 | qT 2,359,296 | kT 4,456,448 | vB 6,553,600
//   opart 8,650,752 (8,388,608) | mpart f32 after | lpart after
// ---------------------------------------------------------------------------
extern "C" void kernel_launch(void* const* d_in, const int* in_sizes, int n_in,
                              void* d_out, int out_size, void* d_ws, size_t ws_size,
                              hipStream_t stream) {
    const float* x       = (const float*)d_in[0];
    const float* w_embed = (const float*)d_in[1];
    const float* b_embed = (const float*)d_in[2];
    const float* w_out   = (const float*)d_in[3];
    const float* b_out   = (const float*)d_in[4];
    float* out = (float*)d_out;

    _Float16* base   = (_Float16*)d_ws;
    _Float16* xT     = base;
    _Float16* yT     = base;             // aliases xT (dead after qkv phase)
    _Float16* wh     = base + 2097152;
    _Float16* w_outT = base + 2293760;
    _Float16* qT     = base + 2359296;
    _Float16* kT     = base + 4456448;
    _Float16* vB     = base + 6553600;
    _Float16* opart  = base + 8650752;
    float*    mpart  = (float*)(opart + (size_t)4 * 8 * N_ * D_);
    float*    lpart  = mpart + (size_t)4 * 8 * N_;

    int dev = 0, coop = 0;
    hipGetDevice(&dev);
    hipDeviceGetAttribute(&coop, hipDeviceAttributeCooperativeLaunch, dev);
    if (coop) {
        void* args[] = { (void*)&x, (void*)&w_embed, (void*)&b_embed, (void*)&w_out,
                         (void*)&b_out, (void*)&xT, (void*)&wh, (void*)&w_outT,
                         (void*)&qT, (void*)&kT, (void*)&vB, (void*)&opart,
                         (void*)&mpart, (void*)&lpart, (void*)&yT, (void*)&out };
        hipError_t e = hipLaunchCooperativeKernel((const void*)mega_kernel,
                                                  dim3(1024), dim3(256), args, 0, stream);
        if (e == hipSuccess) return;
    }

    // Fallback: r11 5-kernel path (143.5 us verified)
    const int splog = 2, nsp = 4;
    prep_kernel   <<<dim3(624, 1, 1), 256, 0, stream>>>(x, w_embed, w_out, xT, wh, w_outT);
    qkv_gemm      <<<dim3(64, 12, 2), 256, 0, stream>>>(xT, wh, b_embed, qT, kT, vB);
    attn_kernel   <<<dim3(32, 4, 2 << splog), 256, 0, stream>>>(qT, kT, vB, opart, mpart, lpart, splog);
    combine_kernel<<<dim3(128, 8, 1), 256, 0, stream>>>(opart, mpart, lpart, yT, nsp);
    proj_gemm     <<<dim3(64, 4, 2),  256, 0, stream>>>(yT, w_outT, b_out, x, out);
}

// Round 13
// 143.075 us; speedup vs baseline: 4.4375x; 4.4375x over previous
//
#include <hip/hip_runtime.h>
#include <hip/hip_bf16.h>

// B=2, C=256, N=4096, heads=4, D=64, 3D=192, M_embed=768
#define NH   4
#define D_   64
#define N_   4096
#define C_   256
#define ME   768
#define QSCALE 0.18033688f   // 0.125 * log2(e): softmax done in exp2 domain

typedef float    f32x4  __attribute__((ext_vector_type(4)));
typedef float    f32x16 __attribute__((ext_vector_type(16)));
typedef _Float16 f16x8  __attribute__((ext_vector_type(8)));
typedef _Float16 f16x4  __attribute__((ext_vector_type(4)));

// ---------------------------------------------------------------------------
// Prep: blocks [0,512): x fp32 [b][c][n] -> xT f16 [b][n][c]
//       blocks [512,528): w_out [k][c] -> w_outT f16 [c][k]
// (wh copy removed: qkv now converts w_embed fp32 on the fly)
// ---------------------------------------------------------------------------
__global__ __launch_bounds__(256) void prep_kernel(const float* __restrict__ x,
                                                   const float* __restrict__ w_out,
                                                   _Float16* __restrict__ xT,
                                                   _Float16* __restrict__ w_outT) {
    __shared__ float T[64][68];
    const int t = threadIdx.x, bx = blockIdx.x;
    if (bx < 512) {
        const int n0 = (bx & 63) * 64, c0 = ((bx >> 6) & 3) * 64, b = bx >> 8;
        const float* xp = x + ((size_t)b * C_ + c0) * N_ + n0;
        #pragma unroll
        for (int r = 0; r < 4; ++r) {
            int idx = r * 256 + t;
            int c = idx >> 4, ng = (idx & 15) * 4;
            *(f32x4*)&T[c][ng] = *(const f32x4*)(xp + (size_t)c * N_ + ng);
        }
        __syncthreads();
        _Float16* dp = xT + ((size_t)b * N_ + n0) * C_ + c0;
        #pragma unroll
        for (int r = 0; r < 2; ++r) {
            int idx = r * 256 + t;
            int n = idx >> 3, cg = (idx & 7) * 8;
            f16x8 v;
            #pragma unroll
            for (int j = 0; j < 8; ++j) v[j] = (_Float16)T[cg + j][n];
            *(f16x8*)(dp + (size_t)n * C_ + cg) = v;
        }
    } else {
        int tile = bx - 512;
        int tc = tile & 3, tk = tile >> 2;
        #pragma unroll
        for (int r = 0; r < 4; ++r) {
            int idx = r * 256 + t;
            int kl = idx >> 4, cl = (idx & 15) * 4;
            *(f32x4*)&T[kl][cl] = *(const f32x4*)(w_out + (size_t)(tk * 64 + kl) * C_ + tc * 64 + cl);
        }
        __syncthreads();
        #pragma unroll
        for (int r = 0; r < 2; ++r) {
            int idx = r * 256 + t;
            int cl = idx >> 3, kg = (idx & 7) * 8;
            f16x8 v;
            #pragma unroll
            for (int j = 0; j < 8; ++j) v[j] = (_Float16)T[kg + j][cl];
            *(f16x8*)(w_outT + (size_t)(tc * 64 + cl) * C_ + tk * 64 + kg) = v;
        }
    }
}

// ---------------------------------------------------------------------------
// QKV GEMM (f16 MFMA 16x16x32). A staged directly from fp32 w_embed with
// on-the-fly f16 convert (wh buffer removed). Register prefetch of next
// K-tile (r11 verified). Epilogue routes qT/kT [n][d] or vB [d][n];
// q pre-scaled by QSCALE.
// ---------------------------------------------------------------------------
__global__ __launch_bounds__(256) void qkv_gemm(const _Float16* __restrict__ xT,
                                                const float* __restrict__ w_embed,
                                                const float* __restrict__ b_embed,
                                                _Float16* __restrict__ qT,
                                                _Float16* __restrict__ kT,
                                                _Float16* __restrict__ vB) {
    __shared__ __align__(16) union SM {
        struct { _Float16 A[64][40], X[64][40]; } s;
        float Os[64][68];
    } sm;
    const int n0 = blockIdx.x * 64, mt = blockIdx.y, b = blockIdx.z;
    const int m0 = mt * 64;
    const int t = threadIdx.x;
    const int lane = t & 63, w = t >> 6, quad = lane >> 4, l16 = lane & 15;
    const int srow = t >> 2, skoff = (t & 3) * 8;
    const int h = mt / 3, r3 = mt - h * 3;
    const float oscale = (r3 == 0) ? QSCALE : 1.0f;
    const float* ap = w_embed + (size_t)(m0 + srow) * C_ + skoff;
    const _Float16* xp = xT + ((size_t)b * N_ + n0 + srow) * C_ + skoff;
    f32x4 a0pre = *(const f32x4*)(ap);
    f32x4 a1pre = *(const f32x4*)(ap + 4);
    f16x8 xpre  = *(const f16x8*)(xp);
    f32x4 acc[4] = {};
    for (int k0 = 0; k0 < C_; k0 += 32) {
        __syncthreads();
        {
            f16x8 av = { (_Float16)a0pre[0], (_Float16)a0pre[1], (_Float16)a0pre[2], (_Float16)a0pre[3],
                         (_Float16)a1pre[0], (_Float16)a1pre[1], (_Float16)a1pre[2], (_Float16)a1pre[3] };
            *(f16x8*)&sm.s.A[srow][skoff] = av;
            *(f16x8*)&sm.s.X[srow][skoff] = xpre;
        }
        __syncthreads();
        if (k0 + 32 < C_) {
            a0pre = *(const f32x4*)(ap + k0 + 32);
            a1pre = *(const f32x4*)(ap + k0 + 36);
            xpre  = *(const f16x8*)(xp + k0 + 32);
        }
        f16x8 af = *(const f16x8*)&sm.s.A[w * 16 + l16][quad * 8];
        #pragma unroll
        for (int nb = 0; nb < 4; ++nb) {
            f16x8 bf = *(const f16x8*)&sm.s.X[nb * 16 + l16][quad * 8];
            acc[nb] = __builtin_amdgcn_mfma_f32_16x16x32_f16(af, bf, acc[nb], 0, 0, 0);
        }
    }
    float bias[4];
    #pragma unroll
    for (int rg = 0; rg < 4; ++rg) bias[rg] = b_embed[m0 + w * 16 + quad * 4 + rg];
    __syncthreads();
    #pragma unroll
    for (int nb = 0; nb < 4; ++nb)
        #pragma unroll
        for (int rg = 0; rg < 4; ++rg)
            sm.Os[w * 16 + quad * 4 + rg][nb * 16 + l16] = (acc[nb][rg] + bias[rg]) * oscale;
    __syncthreads();
    const int bh = b * NH + h;
    if (r3 < 2) {
        _Float16* dst = (r3 ? kT : qT) + ((size_t)bh * N_ + n0) * D_;
        #pragma unroll
        for (int r = 0; r < 2; ++r) {
            int idx = r * 256 + t;
            int n = idx >> 3, mg = (idx & 7) * 8;
            f16x8 v;
            #pragma unroll
            for (int j = 0; j < 8; ++j) v[j] = (_Float16)sm.Os[mg + j][n];
            *(f16x8*)(dst + (size_t)n * D_ + mg) = v;
        }
    } else {
        _Float16* dst = vB + (size_t)bh * D_ * N_ + n0;
        #pragma unroll
        for (int r = 0; r < 2; ++r) {
            int idx = r * 256 + t;
            int d = idx >> 3, ng = (idx & 7) * 8;
            f32x4 a = *(const f32x4*)&sm.Os[d][ng];
            f32x4 b2 = *(const f32x4*)&sm.Os[d][ng + 4];
            f16x8 v = { (_Float16)a[0], (_Float16)a[1], (_Float16)a[2], (_Float16)a[3],
                        (_Float16)b2[0], (_Float16)b2[1], (_Float16)b2[2], (_Float16)b2[3] };
            *(f16x8*)(dst + (size_t)d * N_ + ng) = v;
        }
    }
}

// ---------------------------------------------------------------------------
// Flash attention (r11 verified, untouched): St = K*Q^T (32x32x16);
// PV via 32x32x8f16 zero-shuffle; FIXED-M softmax; single-buffer K/V LDS;
// register prefetch; __launch_bounds__(256,4); nsp=4, grid 1024.
// ---------------------------------------------------------------------------
__global__ __launch_bounds__(256, 4) void attn_kernel(const _Float16* __restrict__ qT,
                                                      const _Float16* __restrict__ kT,
                                                      const _Float16* __restrict__ vB,
                                                      _Float16* __restrict__ opart,
                                                      float* __restrict__ mpart,
                                                      float* __restrict__ lpart,
                                                      int splog) {
    __shared__ __align__(16) union SM {
        struct { _Float16 K[64][76], V[64][76]; } s;
        _Float16 Os[128][76];
    } sm;
    const int t = threadIdx.x;
    const int nsp = 1 << splog;
    const int qt = blockIdx.x, h = blockIdx.y;
    const int b = blockIdx.z >> splog, s = blockIdx.z & (nsp - 1);
    const int bh = b * NH + h, sbh = s * 8 + bh;
    const _Float16* kp = kT + (size_t)bh * N_ * D_;
    const _Float16* vp = vB + (size_t)bh * D_ * N_;
    const int lane = t & 63, w = t >> 6, l32 = lane & 31, hl = lane >> 5;
    const int srow = t >> 3, scol = (t & 7) * 8;

    const _Float16* qp = qT + ((size_t)bh * N_ + qt * 128 + w * 32 + l32) * D_;
    f16x8 qf[4];
    #pragma unroll
    for (int kc = 0; kc < 4; ++kc) qf[kc] = *(const f16x8*)(qp + kc * 16 + hl * 8);

    f32x16 oacc0 = {}, oacc1 = {};
    float m_run = 0.f, l_run = 0.f;

    const int niter = 64 >> splog;
    const int jt_lo = s * niter, jt_hi = jt_lo + niter;
    f16x8 kpre[2], vpre[2];
    #pragma unroll
    for (int r = 0; r < 2; ++r) {
        int row = srow + r * 32;
        kpre[r] = *(const f16x8*)(kp + (size_t)(jt_lo * 64 + row) * D_ + scol);
        vpre[r] = *(const f16x8*)(vp + (size_t)row * N_ + jt_lo * 64 + scol);
    }

    for (int jt = jt_lo; jt < jt_hi; ++jt) {
        __syncthreads();
        #pragma unroll
        for (int r = 0; r < 2; ++r) {
            int row = srow + r * 32;
            *(f16x8*)&sm.s.K[row][scol] = kpre[r];
            *(f16x8*)&sm.s.V[row][scol] = vpre[r];
        }
        __syncthreads();
        if (jt + 1 < jt_hi) {
            #pragma unroll
            for (int r = 0; r < 2; ++r) {
                int row = srow + r * 32;
                kpre[r] = *(const f16x8*)(kp + (size_t)((jt + 1) * 64 + row) * D_ + scol);
                vpre[r] = *(const f16x8*)(vp + (size_t)row * N_ + (jt + 1) * 64 + scol);
            }
        }
        f32x16 sa0 = {}, sa1 = {};
        #pragma unroll
        for (int kc = 0; kc < 4; ++kc) {
            f16x8 kf0 = *(const f16x8*)&sm.s.K[l32][kc * 16 + hl * 8];
            sa0 = __builtin_amdgcn_mfma_f32_32x32x16_f16(kf0, qf[kc], sa0, 0, 0, 0);
            f16x8 kf1 = *(const f16x8*)&sm.s.K[32 + l32][kc * 16 + hl * 8];
            sa1 = __builtin_amdgcn_mfma_f32_32x32x16_f16(kf1, qf[kc], sa1, 0, 0, 0);
        }
        if (jt == jt_lo) {
            f32x16 mm;
            #pragma unroll
            for (int r = 0; r < 16; ++r) mm[r] = fmaxf(sa0[r], sa1[r]);
            f32x4 m4;
            #pragma unroll
            for (int r = 0; r < 4; ++r)
                m4[r] = fmaxf(fmaxf(mm[r], mm[r + 4]), fmaxf(mm[r + 8], mm[r + 12]));
            float mx = fmaxf(fmaxf(m4[0], m4[1]), fmaxf(m4[2], m4[3]));
            mx = fmaxf(mx, __shfl_xor(mx, 32));
            m_run = mx + 8.0f;
        }
        #pragma unroll
        for (int r = 0; r < 16; ++r) sa0[r] = __builtin_amdgcn_exp2f(sa0[r] - m_run);
        #pragma unroll
        for (int r = 0; r < 16; ++r) sa1[r] = __builtin_amdgcn_exp2f(sa1[r] - m_run);
        f32x16 sv = sa0 + sa1;
        f32x4 s4;
        #pragma unroll
        for (int r = 0; r < 4; ++r) s4[r] = (sv[r] + sv[r + 4]) + (sv[r + 8] + sv[r + 12]);
        float rs = (s4[0] + s4[1]) + (s4[2] + s4[3]);
        rs += __shfl_xor(rs, 32);
        l_run += rs;
        #pragma unroll
        for (int jb = 0; jb < 2; ++jb) {
            const f32x16& sa = jb ? sa1 : sa0;
            union BU { f16x4 v; int d[2]; } bf[4];
            #pragma unroll
            for (int q = 0; q < 8; ++q)
                bf[q >> 1].d[q & 1] =
                    __builtin_bit_cast(int, __builtin_amdgcn_cvt_pkrtz(sa[2 * q], sa[2 * q + 1]));
            #pragma unroll
            for (int c = 0; c < 4; ++c) {
                const int vcol = jb * 32 + c * 8 + hl * 4;
                f16x4 va = *(const f16x4*)&sm.s.V[l32][vcol];
                oacc0 = __builtin_amdgcn_mfma_f32_32x32x8f16(va, bf[c].v, oacc0, 0, 0, 0);
                f16x4 vb = *(const f16x4*)&sm.s.V[32 + l32][vcol];
                oacc1 = __builtin_amdgcn_mfma_f32_32x32x8f16(vb, bf[c].v, oacc1, 0, 0, 0);
            }
        }
    }
    float linv = 1.f / l_run;
    if (hl == 0) {
        mpart[(size_t)sbh * N_ + qt * 128 + w * 32 + l32] = m_run;
        lpart[(size_t)sbh * N_ + qt * 128 + w * 32 + l32] = l_run;
    }
    __syncthreads();
    #pragma unroll
    for (int db = 0; db < 2; ++db) {
        const f32x16& oc = db ? oacc1 : oacc0;
        #pragma unroll
        for (int rq = 0; rq < 4; ++rq) {
            f16x4 pv = { (_Float16)(oc[rq * 4 + 0] * linv), (_Float16)(oc[rq * 4 + 1] * linv),
                         (_Float16)(oc[rq * 4 + 2] * linv), (_Float16)(oc[rq * 4 + 3] * linv) };
            *(f16x4*)&sm.Os[w * 32 + l32][db * 32 + rq * 8 + hl * 4] = pv;
        }
    }
    __syncthreads();
    _Float16* op = opart + ((size_t)sbh * N_ + qt * 128) * D_;
    #pragma unroll
    for (int r = 0; r < 4; ++r) {
        int idx = r * 256 + t;
        int i = idx >> 3, ch = (idx & 7) * 8;
        *(f16x8*)(op + (size_t)i * D_ + ch) = *(const f16x8*)&sm.Os[i][ch];
    }
}

// ---------------------------------------------------------------------------
// Projection + FUSED combine, n-major (fixes r9's redundancy): block =
// [128 c x 64 n]; combine weights + Y-strip built ONCE in LDS, then 8 k-steps
// of MFMA. grid(64 nt, 2 ch, 2 b) = 256 blocks (1/CU). Epilogue: bias + x.
// ---------------------------------------------------------------------------
__global__ __launch_bounds__(256) void projc_gemm(const _Float16* __restrict__ opart,
                                                  const float* __restrict__ mpart,
                                                  const float* __restrict__ lpart,
                                                  const _Float16* __restrict__ w_outT,
                                                  const float* __restrict__ b_out,
                                                  const float* __restrict__ x,
                                                  float* __restrict__ out) {
    __shared__ __align__(16) union SMP {
        struct {
            _Float16 Y[64][264];                       // 33792 B (n x k, pad 8)
            union { float W[4][64][4]; _Float16 A[128][40]; } u;  // 10240 B
        } p;
        float Os[128][68];                             // 34816 B (epilogue)
    } sm;
    const int nt = blockIdx.x, chh = blockIdx.y, b = blockIdx.z;
    const int n0 = nt * 64, c0 = chh * 128;
    const int t = threadIdx.x;
    const int lane = t & 63, w = t >> 6, quad = lane >> 4, l16 = lane & 15;

    // phase 0: combine weights W[h][n][s] for this 64-n strip
    {
        const int nl = t & 63, hh = t >> 6;
        const int bh = b * NH + hh;
        float mv[4], lv[4];
        #pragma unroll
        for (int sI = 0; sI < 4; ++sI) {
            mv[sI] = mpart[(size_t)(sI * 8 + bh) * N_ + n0 + nl];
            lv[sI] = lpart[(size_t)(sI * 8 + bh) * N_ + n0 + nl];
        }
        float M = fmaxf(fmaxf(mv[0], mv[1]), fmaxf(mv[2], mv[3]));
        float ws[4], sum = 0.f;
        #pragma unroll
        for (int sI = 0; sI < 4; ++sI) {
            ws[sI] = __builtin_amdgcn_exp2f(mv[sI] - M) * lv[sI];
            sum += ws[sI];
        }
        float inv = 1.f / sum;
        #pragma unroll
        for (int sI = 0; sI < 4; ++sI) sm.p.u.W[hh][nl][sI] = ws[sI] * inv;
    }
    __syncthreads();

    // phase 1: combine 4 split streams -> Y[n][k] f16 (once per block)
    #pragma unroll
    for (int it = 0; it < 8; ++it) {
        int idx = it * 256 + t;
        int n = idx >> 5, kg = (idx & 31) * 8;
        int hh = kg >> 6, d0 = kg & 63;
        const int bh = b * NH + hh;
        const float* Wn = &sm.p.u.W[hh][n][0];
        float accf[8] = {};
        #pragma unroll
        for (int sI = 0; sI < 4; ++sI) {
            f16x8 ov = *(const f16x8*)(opart + ((size_t)(sI * 8 + bh) * N_ + n0 + n) * D_ + d0);
            float wsv = Wn[sI];
            #pragma unroll
            for (int j = 0; j < 8; ++j) accf[j] += wsv * (float)ov[j];
        }
        f16x8 yv;
        #pragma unroll
        for (int j = 0; j < 8; ++j) yv[j] = (_Float16)accf[j];
        *(f16x8*)&sm.p.Y[n][kg] = yv;
    }
    __syncthreads();

    // phase 2: GEMM: 128c x 64n, k-loop over 256. Wave w owns c-blocks 2w,2w+1.
    const int srow = t >> 1, skoff = (t & 1) * 16;   // A stage: 128 rows x 32 k
    const _Float16* ap = w_outT + (size_t)(c0 + srow) * C_ + skoff;
    f16x8 apre0 = *(const f16x8*)(ap);
    f16x8 apre1 = *(const f16x8*)(ap + 8);
    f32x4 acc[2][4] = {};
    for (int k0 = 0; k0 < C_; k0 += 32) {
        __syncthreads();
        *(f16x8*)&sm.p.u.A[srow][skoff]     = apre0;
        *(f16x8*)&sm.p.u.A[srow][skoff + 8] = apre1;
        __syncthreads();
        if (k0 + 32 < C_) {
            apre0 = *(const f16x8*)(ap + k0 + 32);
            apre1 = *(const f16x8*)(ap + k0 + 40);
        }
        #pragma unroll
        for (int cb = 0; cb < 2; ++cb) {
            f16x8 af = *(const f16x8*)&sm.p.u.A[w * 32 + cb * 16 + l16][quad * 8];
            #pragma unroll
            for (int nb = 0; nb < 4; ++nb) {
                f16x8 bf = *(const f16x8*)&sm.p.Y[nb * 16 + l16][k0 + quad * 8];
                acc[cb][nb] = __builtin_amdgcn_mfma_f32_16x16x32_f16(af, bf, acc[cb][nb], 0, 0, 0);
            }
        }
    }
    float bias[2][4];
    #pragma unroll
    for (int cb = 0; cb < 2; ++cb)
        #pragma unroll
        for (int rg = 0; rg < 4; ++rg)
            bias[cb][rg] = b_out[c0 + w * 32 + cb * 16 + quad * 4 + rg];
    __syncthreads();   // Y/A dead; Os aliases them
    #pragma unroll
    for (int cb = 0; cb < 2; ++cb)
        #pragma unroll
        for (int nb = 0; nb < 4; ++nb)
            #pragma unroll
            for (int rg = 0; rg < 4; ++rg)
                sm.Os[w * 32 + cb * 16 + quad * 4 + rg][nb * 16 + l16] =
                    acc[cb][nb][rg] + bias[cb][rg];
    __syncthreads();
    const float* xp = x + ((size_t)b * C_ + c0) * N_ + n0;
    float* op = out + ((size_t)b * C_ + c0) * N_ + n0;
    #pragma unroll
    for (int r = 0; r < 8; ++r) {
        int idx = r * 256 + t;
        int c = idx >> 4, ng = (idx & 15) * 4;
        f32x4 v  = *(const f32x4*)&sm.Os[c][ng];
        f32x4 xv = *(const f32x4*)(xp + (size_t)c * N_ + ng);
        f32x4 o  = { v[0] + xv[0], v[1] + xv[1], v[2] + xv[2], v[3] + xv[3] };
        *(f32x4*)(op + (size_t)c * N_ + ng) = o;
    }
}

// ---------------------------------------------------------------------------
// Workspace (f16 element offsets), nsp=4 (~35 MB):
//   xT 0 (2,097,152) | w_outT 2,293,760 (65,536)
//   qT 2,359,296 | kT 4,456,448 | vB 6,553,600 (2,097,152 each)
//   opart 8,650,752 (8,388,608) | mpart f32 after | lpart after
// ---------------------------------------------------------------------------
extern "C" void kernel_launch(void* const* d_in, const int* in_sizes, int n_in,
                              void* d_out, int out_size, void* d_ws, size_t ws_size,
                              hipStream_t stream) {
    const float* x       = (const float*)d_in[0];
    const float* w_embed = (const float*)d_in[1];
    const float* b_embed = (const float*)d_in[2];
    const float* w_out   = (const float*)d_in[3];
    const float* b_out   = (const float*)d_in[4];
    float* out = (float*)d_out;

    const int splog = 2;   // nsp=4: grid 1024 = 4 blocks/CU, one round

    _Float16* base   = (_Float16*)d_ws;
    _Float16* xT     = base;
    _Float16* w_outT = base + 2293760;
    _Float16* qT     = base + 2359296;
    _Float16* kT     = base + 4456448;
    _Float16* vB     = base + 6553600;
    _Float16* opart  = base + 8650752;
    float*    mpart  = (float*)(opart + (size_t)4 * 8 * N_ * D_);
    float*    lpart  = mpart + (size_t)4 * 8 * N_;

    prep_kernel<<<dim3(528, 1, 1), 256, 0, stream>>>(x, w_out, xT, w_outT);
    qkv_gemm   <<<dim3(64, 12, 2), 256, 0, stream>>>(xT, w_embed, b_embed, qT, kT, vB);
    attn_kernel<<<dim3(32, 4, 2 << splog), 256, 0, stream>>>(qT, kT, vB, opart, mpart, lpart, splog);
    projc_gemm <<<dim3(64, 2, 2),  256, 0, stream>>>(opart, mpart, lpart, w_outT, b_out, x, out);
}